// Round 7
// baseline (346.130 us; speedup 1.0000x reference)
//
#include <hip/hip_runtime.h>
#include <hip/hip_bf16.h>
#include <math.h>

#define FFT_N 8192
#define HWN 196
#define CCH 2048
#define BATCH 16
#define PBLK 28   // blocks per batch
#define PPER 7    // positions per block

// position j (digit-reversed storage after DIF radix-4 x6 + radix-2) -> frequency k
__device__ __forceinline__ int kof(int j) {
    return ((j >> 11) & 3) | (((j >> 9) & 3) << 2) | (((j >> 7) & 3) << 4) |
           (((j >> 5) & 3) << 6) | (((j >> 3) & 3) << 8) | (((j >> 1) & 3) << 10) |
           ((j & 1) << 12);
}
// frequency k -> position j
__device__ __forceinline__ int pof(int k) {
    return ((k & 3) << 11) | (((k >> 2) & 3) << 9) | (((k >> 4) & 3) << 7) |
           (((k >> 6) & 3) << 5) | (((k >> 8) & 3) << 3) | (((k >> 10) & 3) << 1) |
           ((k >> 12) & 1);
}

// per-pass twiddle tables, stride-1 indexed by o: T[OFF+o] = exp(-2*pi*i*o*tstep/N)
// pass1 (tstep=1) stores only o<1024; o>=1024 multiplies by e^{-i*pi/4}.
// layout: 1024 @0, 512 @1024, 128 @1536, 32 @1664, 8 @1696, 2 @1704; total 1706
#define TW_TOTAL 1706

__device__ __forceinline__ float2 cmul(float2 a, float2 b) {
    return make_float2(a.x * b.x - a.y * b.y, a.x * b.y + a.y * b.x);
}

template <int Q4, int OFF>
__device__ __forceinline__ void pass4(float2* z, const float2* T, int tid) {
#pragma unroll
    for (int it = 0; it < FFT_N / 4 / 1024; ++it) {
        int u = tid + 1024 * it;
        int o = u & (Q4 - 1);
        int base = ((u & ~(Q4 - 1)) << 2) | o;
        float2 a = z[base], b = z[base + Q4], c = z[base + 2 * Q4], d = z[base + 3 * Q4];
        float t0r = a.x + c.x, t0i = a.y + c.y, t1r = a.x - c.x, t1i = a.y - c.y;
        float t2r = b.x + d.x, t2i = b.y + d.y, t3r = b.x - d.x, t3i = b.y - d.y;
        float2 u0 = make_float2(t0r + t2r, t0i + t2i);
        float2 u2 = make_float2(t0r - t2r, t0i - t2i);
        float2 u1 = make_float2(t1r + t3i, t1i - t3r);  // t1 - i*t3
        float2 u3 = make_float2(t1r - t3i, t1i + t3r);  // t1 + i*t3
        float2 w1;
        if constexpr (Q4 == 2048) {
            w1 = T[o & 1023];
            if (o & 1024) {
                // * e^{-i*pi/4}
                const float r = 0.70710678118654752f;
                w1 = make_float2(r * (w1.x + w1.y), r * (w1.y - w1.x));
            }
        } else {
            w1 = T[OFF + o];
        }
        float2 w2 = make_float2(w1.x * w1.x - w1.y * w1.y, 2.f * w1.x * w1.y);
        float2 w3 = cmul(w1, w2);
        z[base] = u0;
        z[base + Q4] = cmul(u1, w1);
        z[base + 2 * Q4] = cmul(u2, w2);
        z[base + 3 * Q4] = cmul(u3, w3);
    }
    __syncthreads();
}

// in-place DIF FFT, natural input -> digit-reversed output (order given by kof)
__device__ __forceinline__ void fft8192(float2* z, const float2* T, int tid) {
    pass4<2048, 0>(z, T, tid);
    pass4<512, 1024>(z, T, tid);
    pass4<128, 1536>(z, T, tid);
    pass4<32, 1664>(z, T, tid);
    pass4<8, 1696>(z, T, tid);
    pass4<2, 1704>(z, T, tid);
    // final radix-2 pass on adjacent pairs
#pragma unroll
    for (int it = 0; it < 4; ++it) {
        int u = tid + 1024 * it;
        int i0 = 2 * u, i1 = 2 * u + 1;
        float2 a = z[i0], b = z[i1];
        z[i0] = make_float2(a.x + b.x, a.y + b.y);
        z[i1] = make_float2(a.x - b.x, a.y - b.y);
    }
    __syncthreads();
}

__device__ __forceinline__ void build_tables(float2* T, int tid) {
    const float w0 = -7.66990393942820573e-4f;  // -2*pi/8192
    {  // tstep 1, o < 1024
        float s, c; sincosf(w0 * (float)tid, &s, &c); T[tid] = make_float2(c, s);
    }
    if (tid < 512) {  // tstep 4
        float s, c; sincosf(w0 * (float)(tid * 4), &s, &c); T[1024 + tid] = make_float2(c, s);
    }
    if (tid < 128) {  // tstep 16
        float s, c; sincosf(w0 * (float)(tid * 16), &s, &c); T[1536 + tid] = make_float2(c, s);
    }
    if (tid < 32) {   // tstep 64
        float s, c; sincosf(w0 * (float)(tid * 64), &s, &c); T[1664 + tid] = make_float2(c, s);
    }
    if (tid < 8) {    // tstep 256
        float s, c; sincosf(w0 * (float)(tid * 256), &s, &c); T[1696 + tid] = make_float2(c, s);
    }
    if (tid < 2) {    // tstep 1024
        float s, c; sincosf(w0 * (float)(tid * 1024), &s, &c); T[1704 + tid] = make_float2(c, s);
    }
}

__global__ __launch_bounds__(1024) void cbp_fwd(
    const float* __restrict__ x, const int* __restrict__ h1,
    const int* __restrict__ h2, const int* __restrict__ s1,
    const int* __restrict__ s2, float2* __restrict__ acc) {
    __shared__ float2 z[FFT_N];
    __shared__ float2 T[TW_TOTAL];
    int tid = threadIdx.x;
    int b = blockIdx.x / PBLK;
    int pb = blockIdx.x % PBLK;

    build_tables(T, tid);

    int c0 = tid, c1 = tid + 1024;
    int h1a = h1[c0], h2a = h2[c0], h1b = h1[c1], h2b = h2[c1];
    float g1a = (float)(2 * s1[c0] - 1), g2a = (float)(2 * s2[c0] - 1);
    float g1b = (float)(2 * s1[c1] - 1), g2b = (float)(2 * s2[c1] - 1);

    float accR[8], accI[8];
#pragma unroll
    for (int s = 0; s < 8; s++) { accR[s] = 0.f; accI[s] = 0.f; }

    const float* xa = x + (size_t)b * CCH * HWN + (size_t)c0 * HWN + pb * PPER;
    const float* xc = x + (size_t)b * CCH * HWN + (size_t)c1 * HWN + pb * PPER;

    float v0 = xa[0];
    float v1 = xc[0];

    for (int ip = 0; ip < PPER; ++ip) {
        // prefetch next position's values (hidden under this FFT)
        float nv0 = 0.f, nv1 = 0.f;
        if (ip + 1 < PPER) { nv0 = xa[ip + 1]; nv1 = xc[ip + 1]; }

#pragma unroll
        for (int s = 0; s < 8; s++) z[tid + 1024 * s] = make_float2(0.f, 0.f);
        __syncthreads();
        atomicAdd(&z[h1a].x, g1a * v0);
        atomicAdd(&z[h2a].y, g2a * v0);
        atomicAdd(&z[h1b].x, g1b * v1);
        atomicAdd(&z[h2b].y, g2b * v1);
        __syncthreads();

        fft8192(z, T, tid);

        // P[k] = -i/4 * (Z[k]^2 - conj(Z[N-k])^2), accumulated per position j
#pragma unroll
        for (int s = 0; s < 8; s++) {
            int j = tid + 1024 * s;
            int k = kof(j);
            int m = (FFT_N - k) & (FFT_N - 1);
            int j2 = pof(m);
            float2 a = z[j], bz = z[j2];
            float Dr = (a.x * a.x - a.y * a.y) - (bz.x * bz.x - bz.y * bz.y);
            float Di = 2.f * (a.x * a.y + bz.x * bz.y);
            accR[s] += 0.25f * Di;
            accI[s] -= 0.25f * Dr;
        }
        __syncthreads();
        v0 = nv0; v1 = nv1;
    }

    float2* ab = acc + (size_t)b * FFT_N;
#pragma unroll
    for (int s = 0; s < 8; s++) {
        int j = tid + 1024 * s;
        atomicAdd(&ab[j].x, accR[s]);
        atomicAdd(&ab[j].y, accI[s]);
    }
}

__global__ __launch_bounds__(1024) void cbp_inv(
    const float2* __restrict__ acc, float* __restrict__ out) {
    __shared__ float2 z[FFT_N];
    __shared__ float2 T[TW_TOTAL];
    __shared__ float red[20];
    int tid = threadIdx.x;
    int b = blockIdx.x;

    build_tables(T, tid);

    const float2* ab = acc + (size_t)b * FFT_N;
    // IFFT(P) = conj(FFT(conj(P)))/N; load conj(P) in natural frequency order
#pragma unroll
    for (int s = 0; s < 8; s++) {
        int j = tid + 1024 * s;
        float2 v = ab[j];
        z[kof(j)] = make_float2(v.x, -v.y);
    }
    __syncthreads();

    fft8192(z, T, tid);

    float sv[8];
    float ss = 0.f;
#pragma unroll
    for (int s = 0; s < 8; s++) {
        int j = tid + 1024 * s;
        float v = z[j].x * (1.f / (float)FFT_N);
        float r = copysignf(sqrtf(fabsf(v) + 1e-5f), v);
        sv[s] = r;
        ss += r * r;
    }
    // block reduction of ss
#pragma unroll
    for (int m = 32; m >= 1; m >>= 1) ss += __shfl_xor(ss, m);
    int wave = tid >> 6, lane = tid & 63;
    if (lane == 0) red[wave] = ss;
    __syncthreads();
    if (tid == 0) {
        float tot = 0.f;
        for (int w = 0; w < 16; w++) tot += red[w];
        red[16] = fmaxf(sqrtf(tot), 1e-12f);
    }
    __syncthreads();
    float inv = 1.f / red[16];
    float* ob = out + (size_t)b * FFT_N;
#pragma unroll
    for (int s = 0; s < 8; s++) {
        int j = tid + 1024 * s;
        ob[kof(j)] = sv[s] * inv;
    }
}

extern "C" void kernel_launch(void* const* d_in, const int* in_sizes, int n_in,
                              void* d_out, int out_size, void* d_ws, size_t ws_size,
                              hipStream_t stream) {
    const float* x = (const float*)d_in[0];
    const int* h1 = (const int*)d_in[1];
    const int* h2 = (const int*)d_in[2];
    const int* s1 = (const int*)d_in[3];
    const int* s2 = (const int*)d_in[4];
    float* out = (float*)d_out;
    float2* acc = (float2*)d_ws;

    hipMemsetAsync(acc, 0, (size_t)BATCH * FFT_N * sizeof(float2), stream);
    cbp_fwd<<<BATCH * PBLK, 1024, 0, stream>>>(x, h1, h2, s1, s2, acc);
    cbp_inv<<<BATCH, 1024, 0, stream>>>(acc, (float*)out);
}

// Round 8
// 314.336 us; speedup vs baseline: 1.1011x; 1.1011x over previous
//
#include <hip/hip_runtime.h>
#include <hip/hip_bf16.h>
#include <math.h>

#define FFT_N 8192
#define HWN 196
#define CCH 2048
#define BATCH 16
#define PBLK 14   // blocks per batch
#define PPER 14   // positions per block (processed 2 at a time)

#define ZPAD(i) ((i) + ((i) >> 4))     // pad 1 float2 every 16 -> breaks pow2-stride conflicts
#define ZSZ 8704                        // 8192 + 512 pad

// position j (digit-reversed storage after DIF radix-4 x6 + radix-2) -> frequency k
__device__ __forceinline__ int kof(int j) {
    return ((j >> 11) & 3) | (((j >> 9) & 3) << 2) | (((j >> 7) & 3) << 4) |
           (((j >> 5) & 3) << 6) | (((j >> 3) & 3) << 8) | (((j >> 1) & 3) << 10) |
           ((j & 1) << 12);
}
// frequency k -> position j
__device__ __forceinline__ int pof(int k) {
    return ((k & 3) << 11) | (((k >> 2) & 3) << 9) | (((k >> 4) & 3) << 7) |
           (((k >> 6) & 3) << 5) | (((k >> 8) & 3) << 3) | (((k >> 10) & 3) << 1) |
           ((k >> 12) & 1);
}

// per-pass twiddle tables, stride-1 indexed by o: T[OFF+o] = exp(-2*pi*i*o*tstep/N)
// pass1 (tstep=1) stores only o<1024; o>=1024 multiplies by e^{-i*pi/4}.
// layout: 1024 @0, 512 @1024, 128 @1536, 32 @1664, 8 @1696, 2 @1704; total 1706
#define TW_TOTAL 1706

__device__ __forceinline__ float2 cmul(float2 a, float2 b) {
    return make_float2(a.x * b.x - a.y * b.y, a.x * b.y + a.y * b.x);
}

__device__ __forceinline__ void bf4(float2* z, int i0, int i1, int i2, int i3,
                                    float2 w1, float2 w2, float2 w3) {
    float2 a = z[i0], b = z[i1], c = z[i2], d = z[i3];
    float t0r = a.x + c.x, t0i = a.y + c.y, t1r = a.x - c.x, t1i = a.y - c.y;
    float t2r = b.x + d.x, t2i = b.y + d.y, t3r = b.x - d.x, t3i = b.y - d.y;
    float2 u0 = make_float2(t0r + t2r, t0i + t2i);
    float2 u2 = make_float2(t0r - t2r, t0i - t2i);
    float2 u1 = make_float2(t1r + t3i, t1i - t3r);  // t1 - i*t3
    float2 u3 = make_float2(t1r - t3i, t1i + t3r);  // t1 + i*t3
    z[i0] = u0;
    z[i1] = cmul(u1, w1);
    z[i2] = cmul(u2, w2);
    z[i3] = cmul(u3, w3);
}

template <int Q4, int OFF, bool DUAL>
__device__ __forceinline__ void pass4(float2* z0, float2* z1, const float2* T, int tid) {
#pragma unroll
    for (int it = 0; it < 2; ++it) {
        int u = tid + 1024 * it;
        int o = u & (Q4 - 1);
        int base = ((u & ~(Q4 - 1)) << 2) | o;
        int i0 = ZPAD(base), i1 = ZPAD(base + Q4);
        int i2 = ZPAD(base + 2 * Q4), i3 = ZPAD(base + 3 * Q4);
        float2 w1;
        if constexpr (Q4 == 2048) {
            w1 = T[o & 1023];
            if (o & 1024) {  // * e^{-i*pi/4}
                const float r = 0.70710678118654752f;
                w1 = make_float2(r * (w1.x + w1.y), r * (w1.y - w1.x));
            }
        } else {
            w1 = T[OFF + o];
        }
        float2 w2 = make_float2(w1.x * w1.x - w1.y * w1.y, 2.f * w1.x * w1.y);
        float2 w3 = cmul(w1, w2);
        bf4(z0, i0, i1, i2, i3, w1, w2, w3);
        if constexpr (DUAL) bf4(z1, i0, i1, i2, i3, w1, w2, w3);
    }
    __syncthreads();
}

// in-place DIF FFT (padded layout), natural input -> digit-reversed output (kof order)
template <bool DUAL>
__device__ __forceinline__ void fft8192d(float2* z0, float2* z1, const float2* T, int tid) {
    pass4<2048, 0, DUAL>(z0, z1, T, tid);
    pass4<512, 1024, DUAL>(z0, z1, T, tid);
    pass4<128, 1536, DUAL>(z0, z1, T, tid);
    pass4<32, 1664, DUAL>(z0, z1, T, tid);
    pass4<8, 1696, DUAL>(z0, z1, T, tid);
    pass4<2, 1704, DUAL>(z0, z1, T, tid);
    // final radix-2 pass on adjacent pairs
#pragma unroll
    for (int it = 0; it < 4; ++it) {
        int u = tid + 1024 * it;
        int i0 = ZPAD(2 * u), i1 = ZPAD(2 * u + 1);
        float2 a = z0[i0], b = z0[i1];
        z0[i0] = make_float2(a.x + b.x, a.y + b.y);
        z0[i1] = make_float2(a.x - b.x, a.y - b.y);
        if constexpr (DUAL) {
            float2 c = z1[i0], d = z1[i1];
            z1[i0] = make_float2(c.x + d.x, c.y + d.y);
            z1[i1] = make_float2(c.x - d.x, c.y - d.y);
        }
    }
    __syncthreads();
}

__device__ __forceinline__ void build_tables(float2* T, int tid) {
    const float w0 = -7.66990393942820573e-4f;  // -2*pi/8192
    {  // tstep 1, o < 1024
        float s, c; sincosf(w0 * (float)tid, &s, &c); T[tid] = make_float2(c, s);
    }
    if (tid < 512) {  // tstep 4
        float s, c; sincosf(w0 * (float)(tid * 4), &s, &c); T[1024 + tid] = make_float2(c, s);
    }
    if (tid < 128) {  // tstep 16
        float s, c; sincosf(w0 * (float)(tid * 16), &s, &c); T[1536 + tid] = make_float2(c, s);
    }
    if (tid < 32) {   // tstep 64
        float s, c; sincosf(w0 * (float)(tid * 64), &s, &c); T[1664 + tid] = make_float2(c, s);
    }
    if (tid < 8) {    // tstep 256
        float s, c; sincosf(w0 * (float)(tid * 256), &s, &c); T[1696 + tid] = make_float2(c, s);
    }
    if (tid < 2) {    // tstep 1024
        float s, c; sincosf(w0 * (float)(tid * 1024), &s, &c); T[1704 + tid] = make_float2(c, s);
    }
}

__global__ __launch_bounds__(1024) void cbp_fwd(
    const float* __restrict__ x, const int* __restrict__ h1,
    const int* __restrict__ h2, const int* __restrict__ s1,
    const int* __restrict__ s2, float2* __restrict__ acc) {
    __shared__ float2 zs[2][ZSZ];
    __shared__ float2 T[TW_TOTAL];
    int tid = threadIdx.x;
    int b = blockIdx.x / PBLK;
    int pb = blockIdx.x % PBLK;

    build_tables(T, tid);

    int c0 = tid, c1 = tid + 1024;
    int h1a = ZPAD(h1[c0]), h2a = ZPAD(h2[c0]);
    int h1b = ZPAD(h1[c1]), h2b = ZPAD(h2[c1]);
    float g1a = (float)(2 * s1[c0] - 1), g2a = (float)(2 * s2[c0] - 1);
    float g1b = (float)(2 * s1[c1] - 1), g2b = (float)(2 * s2[c1] - 1);

    float accR[8], accI[8];
#pragma unroll
    for (int s = 0; s < 8; s++) { accR[s] = 0.f; accI[s] = 0.f; }

    // two adjacent positions -> one aligned float2 load per channel
    const float2* pA = (const float2*)(x + ((size_t)b * CCH + c0) * HWN + pb * PPER);
    const float2* pB = (const float2*)(x + ((size_t)b * CCH + c1) * HWN + pb * PPER);

    float2 va = pA[0];  // (.x = pos 2*ii, .y = pos 2*ii+1) for channel c0
    float2 vb = pB[0];  // same for channel c1

    float2* z0 = zs[0];
    float2* z1 = zs[1];
    float* zf = (float*)zs;

    for (int ii = 0; ii < PPER / 2; ++ii) {
        // prefetch next pair (hidden under this iteration's FFTs)
        float2 nva = make_float2(0.f, 0.f), nvb = make_float2(0.f, 0.f);
        if (ii + 1 < PPER / 2) { nva = pA[ii + 1]; nvb = pB[ii + 1]; }

        // zero both padded buffers (flat: 2*ZSZ*2 floats = 34816)
#pragma unroll
        for (int i = 0; i < 34; ++i) zf[tid + 1024 * i] = 0.f;
        __syncthreads();

        atomicAdd(&z0[h1a].x, g1a * va.x);
        atomicAdd(&z0[h2a].y, g2a * va.x);
        atomicAdd(&z0[h1b].x, g1b * vb.x);
        atomicAdd(&z0[h2b].y, g2b * vb.x);
        atomicAdd(&z1[h1a].x, g1a * va.y);
        atomicAdd(&z1[h2a].y, g2a * va.y);
        atomicAdd(&z1[h1b].x, g1b * vb.y);
        atomicAdd(&z1[h2b].y, g2b * vb.y);
        __syncthreads();

        fft8192d<true>(z0, z1, T, tid);

        // P[k] = -i/4 * (Z[k]^2 - conj(Z[N-k])^2), accumulated per position j
#pragma unroll
        for (int s = 0; s < 8; s++) {
            int j = tid + 1024 * s;
            int k = kof(j);
            int m = (FFT_N - k) & (FFT_N - 1);
            int j2 = pof(m);
            int pj = ZPAD(j), pj2 = ZPAD(j2);
            float2 a0 = z0[pj], b0 = z0[pj2];
            float2 a1 = z1[pj], b1 = z1[pj2];
            float Dr = (a0.x * a0.x - a0.y * a0.y) - (b0.x * b0.x - b0.y * b0.y)
                     + (a1.x * a1.x - a1.y * a1.y) - (b1.x * b1.x - b1.y * b1.y);
            float Di = 2.f * (a0.x * a0.y + b0.x * b0.y)
                     + 2.f * (a1.x * a1.y + b1.x * b1.y);
            accR[s] += 0.25f * Di;
            accI[s] -= 0.25f * Dr;
        }
        __syncthreads();
        va = nva; vb = nvb;
    }

    float2* ab = acc + (size_t)b * FFT_N;
#pragma unroll
    for (int s = 0; s < 8; s++) {
        int j = tid + 1024 * s;
        atomicAdd(&ab[j].x, accR[s]);
        atomicAdd(&ab[j].y, accI[s]);
    }
}

__global__ __launch_bounds__(1024) void cbp_inv(
    const float2* __restrict__ acc, float* __restrict__ out) {
    __shared__ float2 z[ZSZ];
    __shared__ float2 T[TW_TOTAL];
    __shared__ float red[20];
    int tid = threadIdx.x;
    int b = blockIdx.x;

    build_tables(T, tid);

    const float2* ab = acc + (size_t)b * FFT_N;
    // IFFT(P) = conj(FFT(conj(P)))/N; load conj(P) in natural frequency order
#pragma unroll
    for (int s = 0; s < 8; s++) {
        int j = tid + 1024 * s;
        float2 v = ab[j];
        z[ZPAD(kof(j))] = make_float2(v.x, -v.y);
    }
    __syncthreads();

    fft8192d<false>(z, z, T, tid);

    float sv[8];
    float ss = 0.f;
#pragma unroll
    for (int s = 0; s < 8; s++) {
        int j = tid + 1024 * s;
        float v = z[ZPAD(j)].x * (1.f / (float)FFT_N);
        float r = copysignf(sqrtf(fabsf(v) + 1e-5f), v);
        sv[s] = r;
        ss += r * r;
    }
    // block reduction of ss
#pragma unroll
    for (int m = 32; m >= 1; m >>= 1) ss += __shfl_xor(ss, m);
    int wave = tid >> 6, lane = tid & 63;
    if (lane == 0) red[wave] = ss;
    __syncthreads();
    if (tid == 0) {
        float tot = 0.f;
        for (int w = 0; w < 16; w++) tot += red[w];
        red[16] = fmaxf(sqrtf(tot), 1e-12f);
    }
    __syncthreads();
    float inv = 1.f / red[16];
    float* ob = out + (size_t)b * FFT_N;
#pragma unroll
    for (int s = 0; s < 8; s++) {
        int j = tid + 1024 * s;
        ob[kof(j)] = sv[s] * inv;
    }
}

extern "C" void kernel_launch(void* const* d_in, const int* in_sizes, int n_in,
                              void* d_out, int out_size, void* d_ws, size_t ws_size,
                              hipStream_t stream) {
    const float* x = (const float*)d_in[0];
    const int* h1 = (const int*)d_in[1];
    const int* h2 = (const int*)d_in[2];
    const int* s1 = (const int*)d_in[3];
    const int* s2 = (const int*)d_in[4];
    float* out = (float*)d_out;
    float2* acc = (float2*)d_ws;

    hipMemsetAsync(acc, 0, (size_t)BATCH * FFT_N * sizeof(float2), stream);
    cbp_fwd<<<BATCH * PBLK, 1024, 0, stream>>>(x, h1, h2, s1, s2, acc);
    cbp_inv<<<BATCH, 1024, 0, stream>>>(acc, (float*)out);
}